// Round 1
// baseline (227.800 us; speedup 1.0000x reference)
//
#include <hip/hip_runtime.h>
#include <cstdint>

#define BATCH   8192
#define KDIM    256
#define HID     64
#define NODES   255
#define BM      128
#define BK      64

typedef unsigned short u16;
typedef short bf16x8 __attribute__((ext_vector_type(8)));
typedef float f32x4  __attribute__((ext_vector_type(4)));

// ---- helpers ---------------------------------------------------------------

__device__ __forceinline__ unsigned int f2bf(float f) {
  // round-to-nearest-even f32 -> bf16 (inputs are finite; no NaN handling needed)
  unsigned int u = __float_as_uint(f);
  return (u + 0x7FFFu + ((u >> 16) & 1u)) >> 16;
}

__device__ __forceinline__ void gld_lds16(const void* g, void* l) {
  // async global->LDS, 16B per lane. LDS dest is wave-uniform base + lane*16,
  // so callers must keep lane->slot contiguous (we do: slot = j*256 + tid).
  typedef __attribute__((address_space(1))) void* gp_t;
  typedef __attribute__((address_space(3))) void* lp_t;
  gp_t gp = reinterpret_cast<gp_t>(reinterpret_cast<uintptr_t>(g));
  lp_t lp = reinterpret_cast<lp_t>(static_cast<unsigned int>(reinterpret_cast<uintptr_t>(l)));
  __builtin_amdgcn_global_load_lds(gp, lp, 16, 0, 0);
}

// ---- kernel 1: fp32 -> bf16 convert (4 elems/thread) -----------------------

__global__ __launch_bounds__(256) void cvt_bf16_kernel(const float* __restrict__ src,
                                                       u16* __restrict__ dst, int n4) {
  int i = blockIdx.x * 256 + threadIdx.x;
  if (i < n4) {
    float4 v = ((const float4*)src)[i];
    uint2 o;
    o.x = f2bf(v.x) | (f2bf(v.y) << 16);
    o.y = f2bf(v.z) | (f2bf(v.w) << 16);
    ((uint2*)dst)[i] = o;
  }
}

// ---- kernel 2: fused  relu(x@W1n^T + b1) @ w2n + b2 -> sigmoid -------------
// block = 256 threads (4 waves), tile = 128 batch rows x 1 node (all 64 hidden)
// wave w computes rows [w*32, w*32+32) x all 64 cols -> full logits for 32 rows

__global__ __launch_bounds__(256, 4) void fused_mlp_kernel(
    const u16* __restrict__ xb,    // [8192][256] bf16 (A, row-major M x K)
    const u16* __restrict__ w1b,   // [255][64][256] bf16 (B^T per node, N x K)
    const float* __restrict__ b1,  // [255][64]
    const float* __restrict__ w2,  // [255][64]
    const float* __restrict__ b2,  // [255]
    float* __restrict__ no_t)      // [255][8192]  node_outputs transposed
{
  // XOR-swizzled granule layout: granule (row, kb) -> slot row*8 + (kb ^ (row&7))
  // -> ds_read_b128 within a quad hits each 4-bank group exactly twice (free).
  __shared__ __align__(16) u16 sA[BM * BK];   // 16 KB, 1024 granules
  __shared__ __align__(16) u16 sB[HID * BK];  //  8 KB,  512 granules
  __shared__ float sLog[BM];

  const int tid  = threadIdx.x;
  const int node = blockIdx.y;
  const int bbase = blockIdx.x * BM;
  const int wave = tid >> 6;
  const int lane = tid & 63;
  const int l16  = lane & 15;
  const int q    = lane >> 4;

  // staging: A needs 4 rounds of 256 granules, B needs 2
  const u16* aSrc[4]; unsigned int aDst[4];
  const u16* bSrc[2]; unsigned int bDst[2];
#pragma unroll
  for (int j = 0; j < 4; ++j) {
    int s = j * 256 + tid;
    int r = s >> 3;
    int kb = (s & 7) ^ (r & 7);
    aSrc[j] = xb + (size_t)(bbase + r) * KDIM + kb * 8;
    aDst[j] = (unsigned int)s * 16u;
  }
#pragma unroll
  for (int j = 0; j < 2; ++j) {
    int s = j * 256 + tid;
    int h = s >> 3;
    int kb = (s & 7) ^ (h & 7);
    bSrc[j] = w1b + (size_t)node * (HID * KDIM) + h * KDIM + kb * 8;
    bDst[j] = (unsigned int)s * 16u;
  }

  // ds_read byte offsets (A frag: lane holds A[m=l16][k=q*8+j]; B mirrors with n=l16)
  unsigned int gA[2][2], gB[4][2];
#pragma unroll
  for (int rt = 0; rt < 2; ++rt)
#pragma unroll
    for (int ks = 0; ks < 2; ++ks) {
      int row = wave * 32 + rt * 16 + l16;
      int kb = ks * 4 + q;
      gA[rt][ks] = (unsigned int)(row * 8 + (kb ^ (row & 7))) * 16u;
    }
#pragma unroll
  for (int ct = 0; ct < 4; ++ct)
#pragma unroll
    for (int ks = 0; ks < 2; ++ks) {
      int h = ct * 16 + l16;
      int kb = ks * 4 + q;
      gB[ct][ks] = (unsigned int)(h * 8 + (kb ^ (h & 7))) * 16u;
    }

  f32x4 acc[2][4];
#pragma unroll
  for (int rt = 0; rt < 2; ++rt)
#pragma unroll
    for (int ct = 0; ct < 4; ++ct)
      acc[rt][ct] = (f32x4){0.f, 0.f, 0.f, 0.f};

  const char* sAc = (const char*)sA;
  const char* sBc = (const char*)sB;

  for (int k0 = 0; k0 < KDIM; k0 += BK) {
    __syncthreads();  // previous iter's LDS readers done
#pragma unroll
    for (int j = 0; j < 4; ++j) gld_lds16(aSrc[j] + k0, (char*)sA + aDst[j]);
#pragma unroll
    for (int j = 0; j < 2; ++j) gld_lds16(bSrc[j] + k0, (char*)sB + bDst[j]);
    __syncthreads();  // drains vmcnt -> staging visible

#pragma unroll
    for (int ks = 0; ks < 2; ++ks) {
      bf16x8 af[2], bfr[4];
#pragma unroll
      for (int rt = 0; rt < 2; ++rt) af[rt] = *(const bf16x8*)(sAc + gA[rt][ks]);
#pragma unroll
      for (int ct = 0; ct < 4; ++ct) bfr[ct] = *(const bf16x8*)(sBc + gB[ct][ks]);
#pragma unroll
      for (int rt = 0; rt < 2; ++rt)
#pragma unroll
        for (int ct = 0; ct < 4; ++ct)
          acc[rt][ct] = __builtin_amdgcn_mfma_f32_16x16x32_bf16(af[rt], bfr[ct], acc[rt][ct], 0, 0, 0);
    }
  }

  // epilogue: h = relu(acc + b1), partial = sum_ct h*w2 ; reduce over 16 lanes
  float b1v[4], w2v[4];
#pragma unroll
  for (int ct = 0; ct < 4; ++ct) {
    int h = ct * 16 + l16;
    b1v[ct] = b1[node * HID + h];
    w2v[ct] = w2[node * HID + h];
  }
#pragma unroll
  for (int rt = 0; rt < 2; ++rt) {
#pragma unroll
    for (int reg = 0; reg < 4; ++reg) {
      float p = 0.f;
#pragma unroll
      for (int ct = 0; ct < 4; ++ct) {
        float hv = acc[rt][ct][reg] + b1v[ct];
        hv = fmaxf(hv, 0.f);
        p += hv * w2v[ct];
      }
      p += __shfl_xor(p, 1);
      p += __shfl_xor(p, 2);
      p += __shfl_xor(p, 4);
      p += __shfl_xor(p, 8);
      // C/D layout: row = q*4+reg (within 16), col = l16 (verified m89/m91)
      if (l16 == 0) sLog[wave * 32 + rt * 16 + q * 4 + reg] = p;
    }
  }
  __syncthreads();
  if (tid < BM) {
    float logit = sLog[tid] + b2[node];
    float sig = 1.0f / (1.0f + expf(-logit));
    no_t[(size_t)node * BATCH + bbase + tid] = sig;  // coalesced 128-float store
  }
}

// ---- kernel 3: soft-decision-tree traversal --------------------------------
// block = 256 threads handles 64 batch rows; thread = (row = tid>>2, sub = tid&3)

__global__ __launch_bounds__(256, 2) void tree_kernel(
    const float* __restrict__ no_t,  // [255][8192]
    const float* __restrict__ leaf,  // [256]
    float* __restrict__ out)
{
  __shared__ float p[64][257];  // +1 pad -> conflict-free both directions
  __shared__ float lw[256];

  const int tid = threadIdx.x;
  const int bbase = blockIdx.x * 64;

  for (int i = tid; i < NODES * 64; i += 256) {
    int n = i >> 6, bl = i & 63;                       // coalesced over b
    p[bl][n] = no_t[(size_t)n * BATCH + bbase + bl];
  }
  lw[tid] = leaf[tid];
  __syncthreads();

  const int row = tid >> 2;
  const int sub = tid & 3;
  const int b = bbase + row;
  const float* pr = p[row];

  float* h_out  = out;
  float* pp_out = out + 8192;                       // path_probs [8192][256]
  float* no_out = out + 8192 + 8192 * 256;          // node_outputs [8192][255]
  float* nr_out = out + 8192 + 8192 * 256 + 8192 * 255;  // node_reach [8192][255]

  // path probs for 64 leaves + h_out partial
  float hacc = 0.f;
  for (int j = sub * 64; j < sub * 64 + 64; ++j) {
    float prod = 1.f;
    int nodei = 0;
#pragma unroll
    for (int lvl = 0; lvl < 8; ++lvl) {
      int bit = (j >> (7 - lvl)) & 1;
      float pv = pr[nodei];
      prod *= bit ? pv : (1.f - pv);
      nodei = 2 * nodei + 1 + bit;
    }
    pp_out[(size_t)b * 256 + j] = prod;
    hacc += prod * lw[j];
  }
  hacc += __shfl_xor(hacc, 1);
  hacc += __shfl_xor(hacc, 2);
  if (sub == 0) h_out[b] = hacc;

  // node_reach (ancestor product, node itself excluded) + node_outputs copy
  int nend = sub * 64 + 64; if (nend > NODES) nend = NODES;
  for (int n = sub * 64; n < nend; ++n) {
    float r = 1.f;
    int m = n;
    while (m > 0) {
      int par = (m - 1) >> 1;
      float pv = pr[par];
      r *= (m == 2 * par + 1) ? (1.f - pv) : pv;
      m = par;
    }
    nr_out[(size_t)b * NODES + n] = r;
    no_out[(size_t)b * NODES + n] = pr[n];
  }
}

// ---- launcher --------------------------------------------------------------

extern "C" void kernel_launch(void* const* d_in, const int* in_sizes, int n_in,
                              void* d_out, int out_size, void* d_ws, size_t ws_size,
                              hipStream_t stream) {
  const float* x    = (const float*)d_in[0];  // [8192][256]
  const float* w1   = (const float*)d_in[1];  // [255][64][256]
  const float* b1   = (const float*)d_in[2];  // [255][64]
  const float* w2   = (const float*)d_in[3];  // [255][64]
  const float* b2   = (const float*)d_in[4];  // [255]
  const float* leaf = (const float*)d_in[5];  // [256][1]
  float* out = (float*)d_out;

  // ws layout: x_bf16 (4 MB) | w1_bf16 (8.36 MB) | no_t (8.36 MB) ~= 21 MB
  char* ws = (char*)d_ws;
  u16*   xb   = (u16*)ws;
  u16*   w1b  = (u16*)(ws + (size_t)4194304);
  float* no_t = (float*)(ws + (size_t)4194304 + 8355840);

  cvt_bf16_kernel<<<2048, 256, 0, stream>>>(x, xb, 524288);     // 8192*256/4
  cvt_bf16_kernel<<<4080, 256, 0, stream>>>(w1, w1b, 1044480);  // 255*64*256/4

  dim3 g(BATCH / BM, NODES);  // (64, 255)
  fused_mlp_kernel<<<g, 256, 0, stream>>>(xb, w1b, b1, w2, b2, no_t);

  tree_kernel<<<BATCH / 64, 256, 0, stream>>>(no_t, leaf, out);
}

// Round 2
// 194.658 us; speedup vs baseline: 1.1703x; 1.1703x over previous
//
#include <hip/hip_runtime.h>
#include <cstdint>

#define BATCH   8192
#define KDIM    256
#define HID     64
#define NODES   255
#define BM      128
#define BN      128   // 2 nodes * 64 hidden
#define BK      64

typedef unsigned short u16;
typedef short bf16x8 __attribute__((ext_vector_type(8)));
typedef float f32x4  __attribute__((ext_vector_type(4)));

// ---- helpers ---------------------------------------------------------------

__device__ __forceinline__ unsigned int f2bf(float f) {
  unsigned int u = __float_as_uint(f);
  return (u + 0x7FFFu + ((u >> 16) & 1u)) >> 16;
}

__device__ __forceinline__ void gld_lds16(const void* g, void* l) {
  // async global->LDS, 16B/lane; LDS dest = wave-uniform base + lane*16
  typedef __attribute__((address_space(1))) void* gp_t;
  typedef __attribute__((address_space(3))) void* lp_t;
  gp_t gp = reinterpret_cast<gp_t>(reinterpret_cast<uintptr_t>(g));
  lp_t lp = reinterpret_cast<lp_t>(static_cast<unsigned int>(reinterpret_cast<uintptr_t>(l)));
  __builtin_amdgcn_global_load_lds(gp, lp, 16, 0, 0);
}

// ---- kernel 1: fp32 -> bf16 convert of x and w1 in one launch --------------

#define NX4  524288    // 8192*256/4
#define NW4  1044480   // 255*64*256/4

__global__ __launch_bounds__(256) void cvt_bf16_kernel(const float* __restrict__ x,
                                                       const float* __restrict__ w1,
                                                       u16* __restrict__ xb,
                                                       u16* __restrict__ w1b) {
  int i = blockIdx.x * 256 + threadIdx.x;
  const float* src; u16* dst; int j;
  if (i < NX4) { src = x; dst = xb; j = i; }
  else { j = i - NX4; if (j >= NW4) return; src = w1; dst = w1b; }
  float4 v = ((const float4*)src)[j];
  uint2 o;
  o.x = f2bf(v.x) | (f2bf(v.y) << 16);
  o.y = f2bf(v.z) | (f2bf(v.w) << 16);
  ((uint2*)dst)[j] = o;
}

// ---- kernel 2: fused  relu(x@W1n^T + b1) @ w2n + b2 -> sigmoid -------------
// block = 256 threads (4 waves), tile = 128 batch rows x 2 nodes (128 hidden)
// wave (wy,wx): rows [wy*64,+64) x node (npair*2+wx)'s 64 hidden cols

__global__ __launch_bounds__(256, 3) void fused_mlp_kernel(
    const u16* __restrict__ xb,    // [8192][256] bf16
    const u16* __restrict__ w1b,   // [256(pad)][64][256] bf16  (N x K rows)
    const float* __restrict__ b1,  // [255][64]
    const float* __restrict__ w2,  // [255][64]
    const float* __restrict__ b2,  // [255]
    float* __restrict__ no_t)      // [255][8192]  node_outputs transposed
{
  // XOR-swizzled granules: (row, kb) -> slot row*8 + (kb ^ (row&7))
  __shared__ __align__(16) u16 sA[BM * BK];   // 16 KB
  __shared__ __align__(16) u16 sB[BN * BK];   // 16 KB
  __shared__ float sLog[2][BM];

  const int tid   = threadIdx.x;
  const int npair = blockIdx.y;
  const int bbase = blockIdx.x * BM;
  const int wave  = tid >> 6;
  const int lane  = tid & 63;
  const int l16   = lane & 15;
  const int q     = lane >> 4;
  const int wy    = wave >> 1;   // M half
  const int wx    = wave & 1;    // node within pair

  // staging: A and B each 1024 granules -> 4 insts each
  const u16* aSrc[4]; unsigned int aDst[4];
  const u16* bSrc[4]; unsigned int bDst[4];
#pragma unroll
  for (int j = 0; j < 4; ++j) {
    int s = j * 256 + tid;
    int r = s >> 3;
    int kb = (s & 7) ^ (r & 7);
    aSrc[j] = xb + (size_t)(bbase + r) * KDIM + kb * 8;
    aDst[j] = (unsigned int)s * 16u;
    bSrc[j] = w1b + (size_t)(npair * BN + r) * KDIM + kb * 8;
    bDst[j] = (unsigned int)s * 16u;
  }

  // ds_read byte offsets. A frag: lane holds A[m][k=q*8+j]; B mirrors (n rows)
  unsigned int gA[4][2], gB[4][2];
#pragma unroll
  for (int t = 0; t < 4; ++t)
#pragma unroll
    for (int ks = 0; ks < 2; ++ks) {
      int rowA = wy * 64 + t * 16 + l16;
      int rowB = wx * 64 + t * 16 + l16;
      int kb = ks * 4 + q;
      gA[t][ks] = (unsigned int)(rowA * 8 + (kb ^ (rowA & 7))) * 16u;
      gB[t][ks] = (unsigned int)(rowB * 8 + (kb ^ (rowB & 7))) * 16u;
    }

  f32x4 acc[4][4];
#pragma unroll
  for (int rt = 0; rt < 4; ++rt)
#pragma unroll
    for (int ct = 0; ct < 4; ++ct)
      acc[rt][ct] = (f32x4){0.f, 0.f, 0.f, 0.f};

  const char* sAc = (const char*)sA;
  const char* sBc = (const char*)sB;

  for (int k0 = 0; k0 < KDIM; k0 += BK) {
    __syncthreads();
#pragma unroll
    for (int j = 0; j < 4; ++j) gld_lds16(aSrc[j] + k0, (char*)sA + aDst[j]);
#pragma unroll
    for (int j = 0; j < 4; ++j) gld_lds16(bSrc[j] + k0, (char*)sB + bDst[j]);
    __syncthreads();  // drains vmcnt -> staging visible

#pragma unroll
    for (int ks = 0; ks < 2; ++ks) {
      bf16x8 af[4], bfr[4];
#pragma unroll
      for (int t = 0; t < 4; ++t) {
        af[t]  = *(const bf16x8*)(sAc + gA[t][ks]);
        bfr[t] = *(const bf16x8*)(sBc + gB[t][ks]);
      }
#pragma unroll
      for (int rt = 0; rt < 4; ++rt)
#pragma unroll
        for (int ct = 0; ct < 4; ++ct)
          acc[rt][ct] = __builtin_amdgcn_mfma_f32_16x16x32_bf16(af[rt], bfr[ct], acc[rt][ct], 0, 0, 0);
    }
  }

  // epilogue: per wave, node = npair*2+wx; lane's hidden idx = ct*16+l16
  const int node  = npair * 2 + wx;
  const int nodeL = node < NODES ? node : NODES - 1;  // clamp for OOB-safe loads
  float b1v[4], w2v[4];
#pragma unroll
  for (int ct = 0; ct < 4; ++ct) {
    int h = ct * 16 + l16;
    b1v[ct] = b1[nodeL * HID + h];
    w2v[ct] = w2[nodeL * HID + h];
  }
#pragma unroll
  for (int rt = 0; rt < 4; ++rt) {
#pragma unroll
    for (int reg = 0; reg < 4; ++reg) {
      float p = 0.f;
#pragma unroll
      for (int ct = 0; ct < 4; ++ct) {
        float hv = acc[rt][ct][reg] + b1v[ct];
        hv = fmaxf(hv, 0.f);
        p += hv * w2v[ct];
      }
      p += __shfl_xor(p, 1);
      p += __shfl_xor(p, 2);
      p += __shfl_xor(p, 4);
      p += __shfl_xor(p, 8);
      // C/D layout: row = q*4+reg (within 16-tile), col = l16
      if (l16 == 0) sLog[wx][wy * 64 + rt * 16 + q * 4 + reg] = p;
    }
  }
  __syncthreads();
  {
    int nsel = tid >> 7;            // 0 or 1
    int row  = tid & 127;
    int n    = npair * 2 + nsel;
    if (n < NODES) {
      float logit = sLog[nsel][row] + b2[n];
      float sig = 1.0f / (1.0f + expf(-logit));
      no_t[(size_t)n * BATCH + bbase + row] = sig;  // coalesced per 128 threads
    }
  }
}

// ---- kernel 3: soft-decision-tree traversal --------------------------------
// block = 256 threads (4 waves) handles 32 batch rows; each wave: 8 rows,
// lane-per-node layout, reach via parent shuffle (each product computed once)

__global__ __launch_bounds__(256) void tree_kernel(
    const float* __restrict__ no_t,  // [255][8192]
    const float* __restrict__ leaf,  // [256]
    float* __restrict__ out)
{
  __shared__ float p[32][257];  // +1 pad: staging writes stride-257 conflict-free

  const int tid = threadIdx.x;
  const int bbase = blockIdx.x * 32;
  const int wave = tid >> 6;
  const int lane = tid & 63;

  for (int i = tid; i < NODES * 32; i += 256) {
    int n = i >> 5, r = i & 31;                     // coalesced over b
    p[r][n] = no_t[(size_t)n * BATCH + bbase + r];
  }
  __syncthreads();

  float4 lw = ((const float4*)leaf)[lane];          // leaf[4*lane .. +3]

  float* h_out  = out;
  float* pp_out = out + 8192;                            // [8192][256]
  float* no_out = out + 8192 + 8192 * 256;               // [8192][255]
  float* nr_out = out + 8192 + 8192 * 256 + 8192 * (size_t)NODES;  // [8192][255]

  for (int j = 0; j < 8; ++j) {
    const int r = wave * 8 + j;
    const int b = bbase + r;
    const float* pr = p[r];
    float* nr_b = nr_out + (size_t)b * NODES;

    // levels 0..5 -> level 6 reach via parent shuffle
    float rc = 1.f;  // within-level reach, lane = within-level node idx
#pragma unroll
    for (int L = 0; L < 6; ++L) {
      if (lane < (1 << L)) nr_b[(1 << L) - 1 + lane] = rc;
      float par = __shfl(rc, lane >> 1);
      float pv = pr[(1 << L) - 1 + (lane >> 1)];
      rc = par * ((lane & 1) ? pv : (1.f - pv));
    }
    // level 6: 64 nodes, 1/lane
    nr_b[63 + lane] = rc;
    float p6 = pr[63 + lane];
    // level 7: 2/lane, nodes 127 + 2*lane + k
    float r7a = rc * (1.f - p6), r7b = rc * p6;
    nr_b[127 + 2 * lane]     = r7a;
    nr_b[127 + 2 * lane + 1] = r7b;
    // leaves: 4/lane, idx 4*lane + m
    float p7a = pr[127 + 2 * lane], p7b = pr[127 + 2 * lane + 1];
    float4 pp;
    pp.x = r7a * (1.f - p7a);
    pp.y = r7a * p7a;
    pp.z = r7b * (1.f - p7b);
    pp.w = r7b * p7b;
    ((float4*)(pp_out + (size_t)b * 256))[lane] = pp;  // coalesced 1KB/wave

    // node_outputs copy, coalesced
    float* no_b = no_out + (size_t)b * NODES;
#pragma unroll
    for (int k = 0; k < 4; ++k) {
      int n = lane + 64 * k;
      if (n < NODES) no_b[n] = pr[n];
    }

    // h_out = pp . leaf
    float hacc = pp.x * lw.x + pp.y * lw.y + pp.z * lw.z + pp.w * lw.w;
    hacc += __shfl_xor(hacc, 1);
    hacc += __shfl_xor(hacc, 2);
    hacc += __shfl_xor(hacc, 4);
    hacc += __shfl_xor(hacc, 8);
    hacc += __shfl_xor(hacc, 16);
    hacc += __shfl_xor(hacc, 32);
    if (lane == 0) h_out[b] = hacc;
  }
}

// ---- launcher --------------------------------------------------------------

extern "C" void kernel_launch(void* const* d_in, const int* in_sizes, int n_in,
                              void* d_out, int out_size, void* d_ws, size_t ws_size,
                              hipStream_t stream) {
  const float* x    = (const float*)d_in[0];
  const float* w1   = (const float*)d_in[1];
  const float* b1   = (const float*)d_in[2];
  const float* w2   = (const float*)d_in[3];
  const float* b2   = (const float*)d_in[4];
  const float* leaf = (const float*)d_in[5];
  float* out = (float*)d_out;

  // ws: xb 4MB | w1b 8MB (padded to 256 nodes; node 255 garbage but finite) | no_t
  char* ws = (char*)d_ws;
  u16*   xb   = (u16*)ws;
  u16*   w1b  = (u16*)(ws + (size_t)4194304);
  float* no_t = (float*)(ws + (size_t)4194304 + 8388608);

  cvt_bf16_kernel<<<(NX4 + NW4 + 255) / 256, 256, 0, stream>>>(x, w1, xb, w1b);

  dim3 g(BATCH / BM, 128);  // (64, 128 node-pairs; pair 127 half-valid)
  fused_mlp_kernel<<<g, 256, 0, stream>>>(xb, w1b, b1, w2, b2, no_t);

  tree_kernel<<<BATCH / 32, 256, 0, stream>>>(no_t, leaf, out);
}

// Round 3
// 193.965 us; speedup vs baseline: 1.1744x; 1.0036x over previous
//
#include <hip/hip_runtime.h>
#include <cstdint>

#define BATCH   8192
#define KDIM    256
#define HID     64
#define NODES   255
#define BCOLS   256   // batch columns per block (4 waves x 64)
#define NPG     16    // nodes per block (loop)

typedef unsigned short u16;
typedef short bf16x8 __attribute__((ext_vector_type(8)));
typedef float f32x16 __attribute__((ext_vector_type(16)));

// ---- helpers ---------------------------------------------------------------

__device__ __forceinline__ unsigned int f2bf(float f) {
  unsigned int u = __float_as_uint(f);
  return (u + 0x7FFFu + ((u >> 16) & 1u)) >> 16;
}

__device__ __forceinline__ void gld_lds16(const void* g, void* l) {
  // async global->LDS, 16B/lane; LDS dest = wave-uniform base + lane*16
  typedef __attribute__((address_space(1))) void* gp_t;
  typedef __attribute__((address_space(3))) void* lp_t;
  gp_t gp = reinterpret_cast<gp_t>(reinterpret_cast<uintptr_t>(g));
  lp_t lp = reinterpret_cast<lp_t>(static_cast<unsigned int>(reinterpret_cast<uintptr_t>(l)));
  __builtin_amdgcn_global_load_lds(gp, lp, 16, 0, 0);
}

// ---- kernel 1: converts + w2/b1 permute ------------------------------------

#define NX4  524288    // 8192*256/4
#define NW4  1044480   // 255*64*256/4
#define NPRM 16320     // 255*64

__global__ __launch_bounds__(256) void cvt_kernel(
    const float* __restrict__ x, const float* __restrict__ w1,
    const float* __restrict__ b1, const float* __restrict__ w2,
    u16* __restrict__ xb, u16* __restrict__ w1b,
    float* __restrict__ b1p, float* __restrict__ w2p) {
  int i = blockIdx.x * 256 + threadIdx.x;
  if (i < NX4 + NW4) {
    const float* src; u16* dst; int j;
    if (i < NX4) { src = x; dst = xb; j = i; }
    else { j = i - NX4; src = w1; dst = w1b; }
    float4 v = ((const float4*)src)[j];
    uint2 o;
    o.x = f2bf(v.x) | (f2bf(v.y) << 16);
    o.y = f2bf(v.z) | (f2bf(v.w) << 16);
    ((uint2*)dst)[j] = o;
  } else {
    int i2 = i - (NX4 + NW4);
    if (i2 < 2 * NPRM) {
      // permute w2/b1 into MFMA C/D register order:
      // out[((node*2+hl)*2+rt)*16+reg] = in[node*64 + rt*32 + (reg&3)+8*(reg>>2)+4*hl]
      int a = i2 >= NPRM;
      int j = a ? i2 - NPRM : i2;
      int reg = j & 15, rt = (j >> 4) & 1, hl = (j >> 5) & 1, node = j >> 6;
      int h = rt * 32 + (reg & 3) + 8 * (reg >> 2) + 4 * hl;
      float v = (a ? b1 : w2)[node * 64 + h];
      (a ? b1p : w2p)[j] = v;
    }
  }
}

// ---- kernel 2: fused MLP, x-resident-in-registers --------------------------
// A = w1[node] (M=64 hidden), B = x (N=batch), 32x32x16 bf16 MFMA.
// Block: 4 waves x 64 batch cols = 256 cols; loops over 16 nodes with
// double-buffered w1 staging (32 KB/node). x frags held in VGPRs (128/wave).

__global__ __launch_bounds__(256, 2) void fused_mlp_kernel(
    const u16* __restrict__ xb,    // [8192][256] bf16
    const u16* __restrict__ w1b,   // [256(pad)][64][256] bf16
    const float* __restrict__ b1p, // [255][2][2][16] permuted
    const float* __restrict__ w2p, // [255][2][2][16] permuted
    const float* __restrict__ b2,  // [255]
    float* __restrict__ no_t)      // [255][8192] node_outputs transposed
{
  // sW granule (h, kb): slot = h*32 + (kb ^ (h&31)) -> ds_read_b128 hits each
  // bank-quad exactly 4x per 32 lanes = inherent-minimum cycles, no conflicts
  __shared__ __align__(16) u16 sW[2][HID * KDIM];  // 2 x 32 KB

  const int tid  = threadIdx.x;
  const int lane = tid & 63;
  const int wv   = tid >> 6;
  const int l31  = lane & 31;
  const int hl   = lane >> 5;
  const int bbase = blockIdx.x * BCOLS;
  const int nbase = blockIdx.y * NPG;

  // ---- load x fragments into registers (once per block) ----
  // B-frag: lane holds B[k][n] with n = l31 (+ct*32), k = ks*16 + hl*8 + j
  bf16x8 xf[2][16];
#pragma unroll
  for (int ct = 0; ct < 2; ++ct) {
    const u16* src = xb + (size_t)(bbase + wv * 64 + ct * 32 + l31) * KDIM + hl * 8;
#pragma unroll
    for (int ks = 0; ks < 16; ++ks)
      xf[ct][ks] = *(const bf16x8*)(src + ks * 16);
  }

  auto stage = [&](int node, int buf) {
#pragma unroll
    for (int j = 0; j < 8; ++j) {
      int s = j * 256 + tid;           // lds slot, contiguous in tid per wave
      int h = s >> 5;
      int kb = (s & 31) ^ (h & 31);
      const u16* g = w1b + (size_t)node * (HID * KDIM) + h * KDIM + kb * 8;
      gld_lds16(g, (char*)(&sW[buf][0]) + (size_t)s * 16u);
    }
  };

  int buf = 0;
  stage(nbase, 0);
  __syncthreads();

  // A-frag slot bases: rt tile rows h = rt*32 + l31 (h&31 == l31)
  const int hbase0 = (l31) * 32;
  const int hbase1 = (32 + l31) * 32;

  for (int i = 0; i < NPG; ++i) {
    const int node = nbase + i;
    if (i + 1 < NPG) stage(nbase + i + 1, buf ^ 1);

    f32x16 acc00 = {0}, acc01 = {0}, acc10 = {0}, acc11 = {0};
    const char* sw = (const char*)&sW[buf][0];

#pragma unroll
    for (int ks = 0; ks < 16; ++ks) {
      int t = (ks * 2 + hl) ^ l31;
      bf16x8 a0 = *(const bf16x8*)(sw + (unsigned int)(hbase0 + t) * 16u);
      bf16x8 a1 = *(const bf16x8*)(sw + (unsigned int)(hbase1 + t) * 16u);
      acc00 = __builtin_amdgcn_mfma_f32_32x32x16_bf16(a0, xf[0][ks], acc00, 0, 0, 0);
      acc01 = __builtin_amdgcn_mfma_f32_32x32x16_bf16(a0, xf[1][ks], acc01, 0, 0, 0);
      acc10 = __builtin_amdgcn_mfma_f32_32x32x16_bf16(a1, xf[0][ks], acc10, 0, 0, 0);
      acc11 = __builtin_amdgcn_mfma_f32_32x32x16_bf16(a1, xf[1][ks], acc11, 0, 0, 0);
    }

    // ---- epilogue: logit[b] = sum_h relu(pre[h][b]+b1[h])*w2[h] ----
    // C/D: col(batch) = l31, row = (reg&3)+8*(reg>>2)+4*hl -> reduction over
    // hidden is in-lane over 32 regs (+1 cross-half shuffle).
    const int nodeL = node < NODES ? node : NODES - 1;
    const float4* w2q = (const float4*)(w2p + ((size_t)nodeL * 2 + hl) * 32);
    const float4* b1q = (const float4*)(b1p + ((size_t)nodeL * 2 + hl) * 32);
    float p0 = 0.f, p1 = 0.f;
#pragma unroll
    for (int rt = 0; rt < 2; ++rt) {
      const f32x16 ac0 = rt ? acc10 : acc00;
      const f32x16 ac1 = rt ? acc11 : acc01;
#pragma unroll
      for (int qd = 0; qd < 4; ++qd) {
        float4 wq = w2q[rt * 4 + qd];
        float4 bq = b1q[rt * 4 + qd];
#pragma unroll
        for (int e = 0; e < 4; ++e) {
          float w = (&wq.x)[e];
          float bb = (&bq.x)[e];
          float h0 = fmaxf(ac0[qd * 4 + e] + bb, 0.f);
          float h1 = fmaxf(ac1[qd * 4 + e] + bb, 0.f);
          p0 += h0 * w;
          p1 += h1 * w;
        }
      }
    }
    p0 += __shfl_xor(p0, 32);
    p1 += __shfl_xor(p1, 32);
    float logit = (hl ? p1 : p0) + b2[nodeL];
    float sig = 1.0f / (1.0f + expf(-logit));
    if (node < NODES)
      no_t[(size_t)node * BATCH + bbase + wv * 64 + lane] = sig;  // 64 contiguous

    __syncthreads();  // staged buf^1 drained (vmcnt0) + readers of buf done
    buf ^= 1;
  }
}

// ---- kernel 3: soft-decision-tree traversal --------------------------------

__global__ __launch_bounds__(256) void tree_kernel(
    const float* __restrict__ no_t,  // [255][8192]
    const float* __restrict__ leaf,  // [256]
    float* __restrict__ out)
{
  __shared__ float p[32][257];

  const int tid = threadIdx.x;
  const int bbase = blockIdx.x * 32;
  const int wave = tid >> 6;
  const int lane = tid & 63;

  for (int i = tid; i < NODES * 32; i += 256) {
    int n = i >> 5, r = i & 31;
    p[r][n] = no_t[(size_t)n * BATCH + bbase + r];
  }
  __syncthreads();

  float4 lw = ((const float4*)leaf)[lane];

  float* h_out  = out;
  float* pp_out = out + 8192;                            // [8192][256]
  float* no_out = out + 8192 + 8192 * 256;               // [8192][255]
  float* nr_out = out + 8192 + 8192 * 256 + 8192 * (size_t)NODES;  // [8192][255]

  for (int j = 0; j < 8; ++j) {
    const int r = wave * 8 + j;
    const int b = bbase + r;
    const float* pr = p[r];
    float* nr_b = nr_out + (size_t)b * NODES;

    float rc = 1.f;
#pragma unroll
    for (int L = 0; L < 6; ++L) {
      if (lane < (1 << L)) nr_b[(1 << L) - 1 + lane] = rc;
      float par = __shfl(rc, lane >> 1);
      float pv = pr[(1 << L) - 1 + (lane >> 1)];
      rc = par * ((lane & 1) ? pv : (1.f - pv));
    }
    nr_b[63 + lane] = rc;
    float p6 = pr[63 + lane];
    float r7a = rc * (1.f - p6), r7b = rc * p6;
    nr_b[127 + 2 * lane]     = r7a;
    nr_b[127 + 2 * lane + 1] = r7b;
    float p7a = pr[127 + 2 * lane], p7b = pr[127 + 2 * lane + 1];
    float4 pp;
    pp.x = r7a * (1.f - p7a);
    pp.y = r7a * p7a;
    pp.z = r7b * (1.f - p7b);
    pp.w = r7b * p7b;
    ((float4*)(pp_out + (size_t)b * 256))[lane] = pp;

    float* no_b = no_out + (size_t)b * NODES;
#pragma unroll
    for (int k = 0; k < 4; ++k) {
      int n = lane + 64 * k;
      if (n < NODES) no_b[n] = pr[n];
    }

    float hacc = pp.x * lw.x + pp.y * lw.y + pp.z * lw.z + pp.w * lw.w;
    hacc += __shfl_xor(hacc, 1);
    hacc += __shfl_xor(hacc, 2);
    hacc += __shfl_xor(hacc, 4);
    hacc += __shfl_xor(hacc, 8);
    hacc += __shfl_xor(hacc, 16);
    hacc += __shfl_xor(hacc, 32);
    if (lane == 0) h_out[b] = hacc;
  }
}

// ---- launcher --------------------------------------------------------------

extern "C" void kernel_launch(void* const* d_in, const int* in_sizes, int n_in,
                              void* d_out, int out_size, void* d_ws, size_t ws_size,
                              hipStream_t stream) {
  const float* x    = (const float*)d_in[0];
  const float* w1   = (const float*)d_in[1];
  const float* b1   = (const float*)d_in[2];
  const float* w2   = (const float*)d_in[3];
  const float* b2   = (const float*)d_in[4];
  const float* leaf = (const float*)d_in[5];
  float* out = (float*)d_out;

  // ws: xb 4MB | w1b 8MB (256-node pad; node 255 poison-but-finite) |
  //     w2p 64KB | b1p 64KB | no_t 8MB
  char* ws = (char*)d_ws;
  u16*   xb   = (u16*)ws;
  u16*   w1b  = (u16*)(ws + (size_t)4194304);
  float* w2p  = (float*)(ws + (size_t)12582912);
  float* b1p  = (float*)(ws + (size_t)12648192);
  float* no_t = (float*)(ws + (size_t)12713472);

  cvt_kernel<<<(NX4 + NW4 + 2 * NPRM + 255) / 256, 256, 0, stream>>>(
      x, w1, b1, w2, xb, w1b, b1p, w2p);

  dim3 g(BATCH / BCOLS, 256 / NPG);  // (32, 16) = 512 blocks, 2/CU
  fused_mlp_kernel<<<g, 256, 0, stream>>>(xb, w1b, b1p, w2p, b2, no_t);

  tree_kernel<<<BATCH / 32, 256, 0, stream>>>(no_t, leaf, out);
}

// Round 4
// 179.164 us; speedup vs baseline: 1.2715x; 1.0826x over previous
//
#include <hip/hip_runtime.h>
#include <cstdint>

#define BATCH   8192
#define KDIM    256
#define HID     64
#define NODES   255
#define NPG     16    // nodes per block

typedef unsigned short u16;
typedef short bf16x8 __attribute__((ext_vector_type(8)));
typedef float f32x16 __attribute__((ext_vector_type(16)));

// ---- helpers ---------------------------------------------------------------

__device__ __forceinline__ unsigned int f2bf(float f) {
  unsigned int u = __float_as_uint(f);
  return (u + 0x7FFFu + ((u >> 16) & 1u)) >> 16;
}

__device__ __forceinline__ void gld_lds16(const void* g, void* l) {
  typedef __attribute__((address_space(1))) void* gp_t;
  typedef __attribute__((address_space(3))) void* lp_t;
  gp_t gp = reinterpret_cast<gp_t>(reinterpret_cast<uintptr_t>(g));
  lp_t lp = reinterpret_cast<lp_t>(static_cast<unsigned int>(reinterpret_cast<uintptr_t>(l)));
  __builtin_amdgcn_global_load_lds(gp, lp, 16, 0, 0);
}

// ---- kernel 1: convert + pack ----------------------------------------------
// xpack: granule g (8 bf16) holds x[col= (g>>10)*32 + (g&31)][k = ((g>>6)&15)*16
//        + ((g>>5)&1)*8 .. +8] -> exact B-fragment order, coalesced loads later.

#define NXG  262144    // 8192*256/8 granules
#define NW4  1044480   // 255*64*256/4
#define NPRM 16320     // 255*64

__global__ __launch_bounds__(256) void cvt_kernel(
    const float* __restrict__ x, const float* __restrict__ w1,
    const float* __restrict__ b1, const float* __restrict__ w2,
    u16* __restrict__ xpack, u16* __restrict__ w1b,
    float* __restrict__ b1p, float* __restrict__ w2p) {
  int i = blockIdx.x * 256 + threadIdx.x;
  if (i < NXG) {
    int g = i;
    int l31 = g & 31, hl = (g >> 5) & 1, ks = (g >> 6) & 15, c = g >> 10;
    const float4* s = (const float4*)(x + ((size_t)(c * 32 + l31)) * KDIM + ks * 16 + hl * 8);
    float4 v0 = s[0], v1 = s[1];
    uint4 o;
    o.x = f2bf(v0.x) | (f2bf(v0.y) << 16);
    o.y = f2bf(v0.z) | (f2bf(v0.w) << 16);
    o.z = f2bf(v1.x) | (f2bf(v1.y) << 16);
    o.w = f2bf(v1.z) | (f2bf(v1.w) << 16);
    ((uint4*)xpack)[g] = o;
  } else if (i < NXG + NW4) {
    int j = i - NXG;
    float4 v = ((const float4*)w1)[j];
    uint2 o;
    o.x = f2bf(v.x) | (f2bf(v.y) << 16);
    o.y = f2bf(v.z) | (f2bf(v.w) << 16);
    ((uint2*)w1b)[j] = o;
  } else {
    int i2 = i - (NXG + NW4);
    if (i2 < 2 * NPRM) {
      // permute w2/b1 into MFMA C/D register order
      int a = i2 >= NPRM;
      int j = a ? i2 - NPRM : i2;
      int reg = j & 15, rt = (j >> 4) & 1, hl = (j >> 5) & 1, node = j >> 6;
      int h = rt * 32 + (reg & 3) + 8 * (reg >> 2) + 4 * hl;
      float v = (a ? b1 : w2)[node * 64 + h];
      (a ? b1p : w2p)[j] = v;
    }
  }
}

// ---- kernel 2: fused MLP ---------------------------------------------------
// A = w1[node] (64 hidden, streamed via LDS dbuf), B = x (batch cols, VGPR-
// resident: 128 cols/wave = xf[4][16] = 256 VGPRs). 1 block/CU, 4 waves.
// Per wave per node: 32 ds_read_b128, 128 MFMA (ratio 4:1).

__global__ __launch_bounds__(256, 1) void fused_mlp_kernel(
    const u16* __restrict__ xpack,  // packed B-frag granules
    const u16* __restrict__ w1b,    // [256(pad)][64][256] bf16
    const float* __restrict__ b1p,  // [255][2][2][16] permuted
    const float* __restrict__ w2p,  // [255][2][2][16] permuted
    const float* __restrict__ b2,   // [255]
    float* __restrict__ no_t)       // [255][8192] node_outputs transposed
{
  // sW granule (h, kb): slot = h*32 + (kb ^ (h&31)); staging writes are
  // tid-contiguous (global_load_lds constraint), reads hit each bank-quad
  // uniformly (round-3 profile: SQ_LDS_BANK_CONFLICT = 0)
  __shared__ __align__(16) u16 sW[2][HID * KDIM];  // 2 x 32 KB

  const int tid  = threadIdx.x;
  const int lane = tid & 63;
  const int wv   = tid >> 6;
  const int l31  = lane & 31;
  const int hl   = lane >> 5;
  const int nbase = blockIdx.y * NPG;
  const int ctile0 = blockIdx.x * 16 + wv * 4;  // wave's first col-tile

  // ---- x fragments: 4 col-tiles x 16 ks, perfectly coalesced loads ----
  bf16x8 xf[4][16];
#pragma unroll
  for (int ct = 0; ct < 4; ++ct) {
    const u16* src = xpack + ((size_t)(ctile0 + ct) * 16) * 512 + lane * 8;
#pragma unroll
    for (int ks = 0; ks < 16; ++ks)
      xf[ct][ks] = *(const bf16x8*)(src + ks * 512);
  }

  // staging offsets (elements within a node's w1 / bytes within buffer)
  int goff[8], loff[8];
#pragma unroll
  for (int j = 0; j < 8; ++j) {
    int s = j * 256 + tid;
    int h = s >> 5;
    int kb = (s & 31) ^ (h & 31);
    goff[j] = h * KDIM + kb * 8;
    loff[j] = s * 16;
  }

  auto stage = [&](int node, int buf) {
    const u16* base = w1b + (size_t)node * (HID * KDIM);
#pragma unroll
    for (int j = 0; j < 8; ++j)
      gld_lds16(base + goff[j], (char*)(&sW[buf][0]) + loff[j]);
  };

  stage(nbase, 0);
  __syncthreads();
  int buf = 0;

  for (int i = 0; i < NPG; ++i) {
    const int node = nbase + i;
    if (i + 1 < NPG) stage(node + 1, buf ^ 1);

    f32x16 acc[2][4];
#pragma unroll
    for (int rt = 0; rt < 2; ++rt)
#pragma unroll
      for (int ct = 0; ct < 4; ++ct) acc[rt][ct] = (f32x16){0};

    const char* sw = (const char*)&sW[buf][0];
#pragma unroll
    for (int ks = 0; ks < 16; ++ks) {
      int t = (ks * 2 + hl) ^ l31;
      bf16x8 a0 = *(const bf16x8*)(sw + (unsigned int)(l31 * 32 + t) * 16u);
      bf16x8 a1 = *(const bf16x8*)(sw + (unsigned int)((32 + l31) * 32 + t) * 16u);
#pragma unroll
      for (int ct = 0; ct < 4; ++ct) {
        acc[0][ct] = __builtin_amdgcn_mfma_f32_32x32x16_bf16(a0, xf[ct][ks], acc[0][ct], 0, 0, 0);
        acc[1][ct] = __builtin_amdgcn_mfma_f32_32x32x16_bf16(a1, xf[ct][ks], acc[1][ct], 0, 0, 0);
      }
    }

    // ---- epilogue: logit[b] = sum_h relu(pre+b1)*w2 (in-lane + 1 shuffle) --
    const int nodeL = node < NODES ? node : NODES - 1;
    const float4* w2q = (const float4*)(w2p + ((size_t)nodeL * 2 + hl) * 32);
    const float4* b1q = (const float4*)(b1p + ((size_t)nodeL * 2 + hl) * 32);
    float p[4] = {0.f, 0.f, 0.f, 0.f};
#pragma unroll
    for (int rt = 0; rt < 2; ++rt)
#pragma unroll
      for (int qd = 0; qd < 4; ++qd) {
        float4 wq = w2q[rt * 4 + qd];
        float4 bq = b1q[rt * 4 + qd];
#pragma unroll
        for (int e = 0; e < 4; ++e) {
          float w = (&wq.x)[e];
          float bb = (&bq.x)[e];
#pragma unroll
          for (int ct = 0; ct < 4; ++ct)
            p[ct] += fmaxf(acc[rt][ct][qd * 4 + e] + bb, 0.f) * w;
        }
      }
    float b2v = b2[nodeL];
#pragma unroll
    for (int ct = 0; ct < 4; ++ct) p[ct] += __shfl_xor(p[ct], 32);

    if (node < NODES) {
      float* dst = no_t + (size_t)node * BATCH + blockIdx.x * 512 + wv * 128;
#pragma unroll
      for (int m = 0; m < 2; ++m) {
        int ct = hl * 2 + m;   // half-wave writes 2 col-tiles -> 128B stores
        float logit = p[ct] + b2v;
        dst[ct * 32 + l31] = 1.0f / (1.0f + expf(-logit));
      }
    }

    __syncthreads();  // staged buf^1 drained + readers of buf done
    buf ^= 1;
  }
}

// ---- kernel 3: soft-decision-tree traversal --------------------------------

__global__ __launch_bounds__(256) void tree_kernel(
    const float* __restrict__ no_t,  // [255][8192]
    const float* __restrict__ leaf,  // [256]
    float* __restrict__ out)
{
  __shared__ float p[32][257];

  const int tid = threadIdx.x;
  const int bbase = blockIdx.x * 32;
  const int wave = tid >> 6;
  const int lane = tid & 63;

  for (int i = tid; i < NODES * 32; i += 256) {
    int n = i >> 5, r = i & 31;
    p[r][n] = no_t[(size_t)n * BATCH + bbase + r];
  }
  __syncthreads();

  float4 lw = ((const float4*)leaf)[lane];

  float* h_out  = out;
  float* pp_out = out + 8192;                            // [8192][256]
  float* no_out = out + 8192 + 8192 * 256;               // [8192][255]
  float* nr_out = out + 8192 + 8192 * 256 + 8192 * (size_t)NODES;  // [8192][255]

  for (int j = 0; j < 8; ++j) {
    const int r = wave * 8 + j;
    const int b = bbase + r;
    const float* pr = p[r];
    float* nr_b = nr_out + (size_t)b * NODES;

    float rc = 1.f;
#pragma unroll
    for (int L = 0; L < 6; ++L) {
      if (lane < (1 << L)) nr_b[(1 << L) - 1 + lane] = rc;
      float par = __shfl(rc, lane >> 1);
      float pv = pr[(1 << L) - 1 + (lane >> 1)];
      rc = par * ((lane & 1) ? pv : (1.f - pv));
    }
    nr_b[63 + lane] = rc;
    float p6 = pr[63 + lane];
    float r7a = rc * (1.f - p6), r7b = rc * p6;
    nr_b[127 + 2 * lane]     = r7a;
    nr_b[127 + 2 * lane + 1] = r7b;
    float p7a = pr[127 + 2 * lane], p7b = pr[127 + 2 * lane + 1];
    float4 pp;
    pp.x = r7a * (1.f - p7a);
    pp.y = r7a * p7a;
    pp.z = r7b * (1.f - p7b);
    pp.w = r7b * p7b;
    ((float4*)(pp_out + (size_t)b * 256))[lane] = pp;

    float* no_b = no_out + (size_t)b * NODES;
#pragma unroll
    for (int k = 0; k < 4; ++k) {
      int n = lane + 64 * k;
      if (n < NODES) no_b[n] = pr[n];
    }

    float hacc = pp.x * lw.x + pp.y * lw.y + pp.z * lw.z + pp.w * lw.w;
    hacc += __shfl_xor(hacc, 1);
    hacc += __shfl_xor(hacc, 2);
    hacc += __shfl_xor(hacc, 4);
    hacc += __shfl_xor(hacc, 8);
    hacc += __shfl_xor(hacc, 16);
    hacc += __shfl_xor(hacc, 32);
    if (lane == 0) h_out[b] = hacc;
  }
}

// ---- launcher --------------------------------------------------------------

extern "C" void kernel_launch(void* const* d_in, const int* in_sizes, int n_in,
                              void* d_out, int out_size, void* d_ws, size_t ws_size,
                              hipStream_t stream) {
  const float* x    = (const float*)d_in[0];
  const float* w1   = (const float*)d_in[1];
  const float* b1   = (const float*)d_in[2];
  const float* w2   = (const float*)d_in[3];
  const float* b2   = (const float*)d_in[4];
  const float* leaf = (const float*)d_in[5];
  float* out = (float*)d_out;

  // ws: xpack 4MB | w1b 8MB (256-node pad; node 255 = 0xAA poison, finite) |
  //     w2p 64KB | b1p 64KB | no_t 8MB
  char* ws = (char*)d_ws;
  u16*   xpack = (u16*)ws;
  u16*   w1b   = (u16*)(ws + (size_t)4194304);
  float* w2p   = (float*)(ws + (size_t)12582912);
  float* b1p   = (float*)(ws + (size_t)12648192);
  float* no_t  = (float*)(ws + (size_t)12713472);

  cvt_kernel<<<(NXG + NW4 + 2 * NPRM + 255) / 256, 256, 0, stream>>>(
      x, w1, b1, w2, xpack, w1b, b1p, w2p);

  dim3 g(16, 16);  // 16 col-blocks (512 cols) x 16 node-groups = 256 blocks
  fused_mlp_kernel<<<g, 256, 0, stream>>>(xpack, w1b, b1p, w2p, b2, no_t);

  tree_kernel<<<BATCH / 32, 256, 0, stream>>>(no_t, leaf, out);
}

// Round 5
// 175.076 us; speedup vs baseline: 1.3011x; 1.0234x over previous
//
#include <hip/hip_runtime.h>
#include <cstdint>

#define BATCH   8192
#define KDIM    256
#define HID     64
#define NODES   255
#define NPG     16    // nodes per block

typedef unsigned short u16;
typedef short bf16x8 __attribute__((ext_vector_type(8)));
typedef float f32x16 __attribute__((ext_vector_type(16)));

// ---- helpers ---------------------------------------------------------------

__device__ __forceinline__ unsigned int f2bf(float f) {
  unsigned int u = __float_as_uint(f);
  return (u + 0x7FFFu + ((u >> 16) & 1u)) >> 16;
}

__device__ __forceinline__ void gld_lds16(const void* g, void* l) {
  typedef __attribute__((address_space(1))) void* gp_t;
  typedef __attribute__((address_space(3))) void* lp_t;
  gp_t gp = reinterpret_cast<gp_t>(reinterpret_cast<uintptr_t>(g));
  lp_t lp = reinterpret_cast<lp_t>(static_cast<unsigned int>(reinterpret_cast<uintptr_t>(l)));
  __builtin_amdgcn_global_load_lds(gp, lp, 16, 0, 0);
}

// ---- kernel 1: convert + pack ----------------------------------------------
// xpack granule g holds x[col=(g>>10)*32+(g&31)][k=((g>>6)&15)*16+((g>>5)&1)*8 ..+8]
// = exact B-fragment order; fused kernel loads it fully coalesced.

#define NXG  262144    // 8192*256/8 granules
#define NW4  1044480   // 255*64*256/4
#define NPRM 16320     // 255*64

__global__ __launch_bounds__(256) void cvt_kernel(
    const float* __restrict__ x, const float* __restrict__ w1,
    const float* __restrict__ b1, const float* __restrict__ w2,
    u16* __restrict__ xpack, u16* __restrict__ w1b,
    float* __restrict__ b1p, float* __restrict__ w2p) {
  int i = blockIdx.x * 256 + threadIdx.x;
  if (i < NXG) {
    int g = i;
    int l31 = g & 31, hl = (g >> 5) & 1, ks = (g >> 6) & 15, c = g >> 10;
    const float4* s = (const float4*)(x + ((size_t)(c * 32 + l31)) * KDIM + ks * 16 + hl * 8);
    float4 v0 = s[0], v1 = s[1];
    uint4 o;
    o.x = f2bf(v0.x) | (f2bf(v0.y) << 16);
    o.y = f2bf(v0.z) | (f2bf(v0.w) << 16);
    o.z = f2bf(v1.x) | (f2bf(v1.y) << 16);
    o.w = f2bf(v1.z) | (f2bf(v1.w) << 16);
    ((uint4*)xpack)[g] = o;
  } else if (i < NXG + NW4) {
    int j = i - NXG;
    float4 v = ((const float4*)w1)[j];
    uint2 o;
    o.x = f2bf(v.x) | (f2bf(v.y) << 16);
    o.y = f2bf(v.z) | (f2bf(v.w) << 16);
    ((uint2*)w1b)[j] = o;
  } else {
    int i2 = i - (NXG + NW4);
    if (i2 < 2 * NPRM) {
      // permute w2/b1 into MFMA C/D register order
      int a = i2 >= NPRM;
      int j = a ? i2 - NPRM : i2;
      int reg = j & 15, rt = (j >> 4) & 1, hl = (j >> 5) & 1, node = j >> 6;
      int h = rt * 32 + (reg & 3) + 8 * (reg >> 2) + 4 * hl;
      float v = (a ? b1 : w2)[node * 64 + h];
      (a ? b1p : w2p)[j] = v;
    }
  }
}

// ---- kernel 2: fused MLP ---------------------------------------------------
// A = w1[node] (LDS dbuf), B = x (VGPR-resident, 64 cols/wave = xf[2][16] =
// 128 VGPRs). 2 blocks/CU (8 waves) so epilogue VALU / ds_read latency of one
// block overlaps MFMA of the other (m114 co-scheduling).
// Per wave per node: 32 ds_read_b128, 64 MFMA.

__global__ __launch_bounds__(256, 2) void fused_mlp_kernel(
    const u16* __restrict__ xpack,  // packed B-frag granules
    const u16* __restrict__ w1b,    // [256(pad)][64][256] bf16
    const float* __restrict__ b1p,  // [255][2][2][16] permuted
    const float* __restrict__ w2p,  // [255][2][2][16] permuted
    const float* __restrict__ b2,   // [255]
    float* __restrict__ no_t)       // [255][8192] node_outputs transposed
{
  // sW granule (h, kb): slot = h*32 + (kb ^ (h&31)); staging writes are
  // tid-contiguous (global_load_lds constraint); reads conflict-free (R3/R4: 0)
  __shared__ __align__(16) u16 sW[2][HID * KDIM];  // 2 x 32 KB

  const int tid  = threadIdx.x;
  const int lane = tid & 63;
  const int wv   = tid >> 6;
  const int l31  = lane & 31;
  const int hl   = lane >> 5;
  const int nbase = blockIdx.y * NPG;
  const int ctile0 = blockIdx.x * 8 + wv * 2;  // wave's first 32-col tile

  // ---- x fragments: 2 col-tiles x 16 ks, perfectly coalesced ----
  bf16x8 xf[2][16];
#pragma unroll
  for (int ct = 0; ct < 2; ++ct) {
    const u16* src = xpack + ((size_t)(ctile0 + ct) * 16) * 512 + lane * 8;
#pragma unroll
    for (int ks = 0; ks < 16; ++ks)
      xf[ct][ks] = *(const bf16x8*)(src + ks * 512);
  }

  auto stage = [&](int node, int buf) {
    const u16* base = w1b + (size_t)node * (HID * KDIM);
    char* lb = (char*)(&sW[buf][0]);
#pragma unroll
    for (int j = 0; j < 8; ++j) {
      int s = j * 256 + tid;
      int h = s >> 5;
      int kb = (s & 31) ^ (h & 31);
      gld_lds16(base + h * KDIM + kb * 8, lb + s * 16);
    }
  };

  stage(nbase, 0);
  __syncthreads();
  int buf = 0;

  for (int i = 0; i < NPG; ++i) {
    const int node = nbase + i;
    if (i + 1 < NPG) stage(node + 1, buf ^ 1);

    f32x16 acc[2][2];
#pragma unroll
    for (int rt = 0; rt < 2; ++rt)
#pragma unroll
      for (int ct = 0; ct < 2; ++ct) acc[rt][ct] = (f32x16){0};

    const char* sw = (const char*)&sW[buf][0];
#pragma unroll
    for (int ks = 0; ks < 16; ++ks) {
      int t = (ks * 2 + hl) ^ l31;
      bf16x8 a0 = *(const bf16x8*)(sw + (unsigned int)(l31 * 32 + t) * 16u);
      bf16x8 a1 = *(const bf16x8*)(sw + (unsigned int)((32 + l31) * 32 + t) * 16u);
#pragma unroll
      for (int ct = 0; ct < 2; ++ct) {
        acc[0][ct] = __builtin_amdgcn_mfma_f32_32x32x16_bf16(a0, xf[ct][ks], acc[0][ct], 0, 0, 0);
        acc[1][ct] = __builtin_amdgcn_mfma_f32_32x32x16_bf16(a1, xf[ct][ks], acc[1][ct], 0, 0, 0);
      }
    }

    // ---- epilogue: logit[b] = sum_h relu(pre+b1)*w2 (in-lane + 1 shuffle) --
    const int nodeL = node < NODES ? node : NODES - 1;
    const float4* w2q = (const float4*)(w2p + ((size_t)nodeL * 2 + hl) * 32);
    const float4* b1q = (const float4*)(b1p + ((size_t)nodeL * 2 + hl) * 32);
    float p0 = 0.f, p1 = 0.f;
#pragma unroll
    for (int rt = 0; rt < 2; ++rt)
#pragma unroll
      for (int qd = 0; qd < 4; ++qd) {
        float4 wq = w2q[rt * 4 + qd];
        float4 bq = b1q[rt * 4 + qd];
#pragma unroll
        for (int e = 0; e < 4; ++e) {
          float w = (&wq.x)[e];
          float bb = (&bq.x)[e];
          p0 += fmaxf(acc[rt][0][qd * 4 + e] + bb, 0.f) * w;
          p1 += fmaxf(acc[rt][1][qd * 4 + e] + bb, 0.f) * w;
        }
      }
    p0 += __shfl_xor(p0, 32);
    p1 += __shfl_xor(p1, 32);

    if (node < NODES) {
      float logit = (hl ? p1 : p0) + b2[nodeL];
      float sig = 1.0f / (1.0f + expf(-logit));
      // col = ctile0*32 + hl*32 + l31 -> 64 contiguous floats per wave
      no_t[(size_t)node * BATCH + blockIdx.x * 256 + wv * 64 + lane] = sig;
    }

    __syncthreads();  // staged buf^1 drained + readers of buf done
    buf ^= 1;
  }
}

// ---- kernel 3: soft-decision-tree traversal --------------------------------
// 512 blocks x 16 rows; wave handles 4 rows serially (2x parallelism vs R4)

__global__ __launch_bounds__(256) void tree_kernel(
    const float* __restrict__ no_t,  // [255][8192]
    const float* __restrict__ leaf,  // [256]
    float* __restrict__ out)
{
  __shared__ float p[16][257];

  const int tid = threadIdx.x;
  const int bbase = blockIdx.x * 16;
  const int wave = tid >> 6;
  const int lane = tid & 63;

  for (int i = tid; i < NODES * 16; i += 256) {
    int n = i >> 4, r = i & 15;
    p[r][n] = no_t[(size_t)n * BATCH + bbase + r];
  }
  __syncthreads();

  float4 lw = ((const float4*)leaf)[lane];

  float* h_out  = out;
  float* pp_out = out + 8192;                            // [8192][256]
  float* no_out = out + 8192 + 8192 * 256;               // [8192][255]
  float* nr_out = out + 8192 + 8192 * 256 + 8192 * (size_t)NODES;  // [8192][255]

  for (int j = 0; j < 4; ++j) {
    const int r = wave * 4 + j;
    const int b = bbase + r;
    const float* pr = p[r];
    float* nr_b = nr_out + (size_t)b * NODES;

    float rc = 1.f;
#pragma unroll
    for (int L = 0; L < 6; ++L) {
      if (lane < (1 << L)) nr_b[(1 << L) - 1 + lane] = rc;
      float par = __shfl(rc, lane >> 1);
      float pv = pr[(1 << L) - 1 + (lane >> 1)];
      rc = par * ((lane & 1) ? pv : (1.f - pv));
    }
    nr_b[63 + lane] = rc;
    float p6 = pr[63 + lane];
    float r7a = rc * (1.f - p6), r7b = rc * p6;
    nr_b[127 + 2 * lane]     = r7a;
    nr_b[127 + 2 * lane + 1] = r7b;
    float p7a = pr[127 + 2 * lane], p7b = pr[127 + 2 * lane + 1];
    float4 pp;
    pp.x = r7a * (1.f - p7a);
    pp.y = r7a * p7a;
    pp.z = r7b * (1.f - p7b);
    pp.w = r7b * p7b;
    ((float4*)(pp_out + (size_t)b * 256))[lane] = pp;

    float* no_b = no_out + (size_t)b * NODES;
#pragma unroll
    for (int k = 0; k < 4; ++k) {
      int n = lane + 64 * k;
      if (n < NODES) no_b[n] = pr[n];
    }

    float hacc = pp.x * lw.x + pp.y * lw.y + pp.z * lw.z + pp.w * lw.w;
    hacc += __shfl_xor(hacc, 1);
    hacc += __shfl_xor(hacc, 2);
    hacc += __shfl_xor(hacc, 4);
    hacc += __shfl_xor(hacc, 8);
    hacc += __shfl_xor(hacc, 16);
    hacc += __shfl_xor(hacc, 32);
    if (lane == 0) h_out[b] = hacc;
  }
}

// ---- launcher --------------------------------------------------------------

extern "C" void kernel_launch(void* const* d_in, const int* in_sizes, int n_in,
                              void* d_out, int out_size, void* d_ws, size_t ws_size,
                              hipStream_t stream) {
  const float* x    = (const float*)d_in[0];
  const float* w1   = (const float*)d_in[1];
  const float* b1   = (const float*)d_in[2];
  const float* w2   = (const float*)d_in[3];
  const float* b2   = (const float*)d_in[4];
  const float* leaf = (const float*)d_in[5];
  float* out = (float*)d_out;

  // ws: xpack 4MB | w1b 8MB (256-node pad; node 255 = poison-but-finite) |
  //     w2p 64KB | b1p 64KB | no_t 8MB
  char* ws = (char*)d_ws;
  u16*   xpack = (u16*)ws;
  u16*   w1b   = (u16*)(ws + (size_t)4194304);
  float* w2p   = (float*)(ws + (size_t)12582912);
  float* b1p   = (float*)(ws + (size_t)12648192);
  float* no_t  = (float*)(ws + (size_t)12713472);

  cvt_kernel<<<(NXG + NW4 + 2 * NPRM + 255) / 256, 256, 0, stream>>>(
      x, w1, b1, w2, xpack, w1b, b1p, w2p);

  dim3 g(32, 16);  // 32 col-blocks (256 cols) x 16 node-groups = 512 blocks
  fused_mlp_kernel<<<g, 256, 0, stream>>>(xpack, w1b, b1p, w2p, b2, no_t);

  tree_kernel<<<BATCH / 16, 256, 0, stream>>>(no_t, leaf, out);
}

// Round 6
// 159.792 us; speedup vs baseline: 1.4256x; 1.0957x over previous
//
#include <hip/hip_runtime.h>
#include <cstdint>

#define BATCH   8192
#define KDIM    256
#define HID     64
#define NODES   255
#define NPG     16    // nodes per block group

typedef unsigned short u16;
typedef short bf16x8 __attribute__((ext_vector_type(8)));
typedef float f32x16 __attribute__((ext_vector_type(16)));

// ---- helpers ---------------------------------------------------------------

__device__ __forceinline__ unsigned int f2bf(float f) {
  unsigned int u = __float_as_uint(f);
  return (u + 0x7FFFu + ((u >> 16) & 1u)) >> 16;
}

__device__ __forceinline__ void gld_lds16(const void* g, void* l) {
  // async global->LDS, 16B/lane; LDS dest = wave-uniform base + lane*16
  typedef __attribute__((address_space(1))) void* gp_t;
  typedef __attribute__((address_space(3))) void* lp_t;
  gp_t gp = reinterpret_cast<gp_t>(reinterpret_cast<uintptr_t>(g));
  lp_t lp = reinterpret_cast<lp_t>(static_cast<unsigned int>(reinterpret_cast<uintptr_t>(l)));
  __builtin_amdgcn_global_load_lds(gp, lp, 16, 0, 0);
}

// ---- kernel 1: convert + pack (block-role split) ---------------------------
// blocks [0,256): x -> xpack via LDS transpose (coalesced reads AND writes)
// blocks [256,4336): w1 fp32->bf16, fully coalesced
// blocks [4336,4464): w2/b1 permute into MFMA C/D register order

#define NW4  1044480   // 255*64*256/4
#define NPRM 16320     // 255*64

__global__ __launch_bounds__(256) void cvt_kernel(
    const float* __restrict__ x, const float* __restrict__ w1,
    const float* __restrict__ b1, const float* __restrict__ w2,
    u16* __restrict__ xpack, u16* __restrict__ w1b,
    float* __restrict__ b1p, float* __restrict__ w2p) {
  const int tid = threadIdx.x;
  const int blk = blockIdx.x;

  if (blk < 256) {
    // one 32-col x tile: load 32x256 fp32 coalesced, transpose-pack via LDS
    __shared__ u16 sT[32 * 268];  // pad 268: b64 reads 2-way only (free)
    const float* xs = x + (size_t)blk * 32 * KDIM;
#pragma unroll
    for (int j = 0; j < 8; ++j) {
      int idx = j * 256 + tid;             // 2048 float4s, contiguous
      float4 v = ((const float4*)xs)[idx];
      int row = idx >> 6, f4 = idx & 63;
      uint2 o;
      o.x = f2bf(v.x) | (f2bf(v.y) << 16);
      o.y = f2bf(v.z) | (f2bf(v.w) << 16);
      *(uint2*)&sT[row * 268 + f4 * 4] = o;
    }
    __syncthreads();
#pragma unroll
    for (int j = 0; j < 4; ++j) {
      int d = j * 256 + tid;               // granule: ks*64 + hl*32 + l31
      int ks = d >> 6, hl = (d >> 5) & 1, l31 = d & 31;
      const u16* s8 = &sT[l31 * 268 + ks * 16 + hl * 8];
      uint2 lo = *(const uint2*)s8;
      uint2 hi = *(const uint2*)(s8 + 4);
      uint4 o = {lo.x, lo.y, hi.x, hi.y};
      ((uint4*)xpack)[(size_t)blk * 1024 + d] = o;  // coalesced granule write
    }
  } else if (blk < 4336) {
    int j = (blk - 256) * 256 + tid;       // exactly NW4 threads
    float4 v = ((const float4*)w1)[j];
    uint2 o;
    o.x = f2bf(v.x) | (f2bf(v.y) << 16);
    o.y = f2bf(v.z) | (f2bf(v.w) << 16);
    ((uint2*)w1b)[j] = o;
  } else {
    int i2 = (blk - 4336) * 256 + tid;
    if (i2 < 2 * NPRM) {
      int a = i2 >= NPRM;
      int j = a ? i2 - NPRM : i2;
      int reg = j & 15, rt = (j >> 4) & 1, hl = (j >> 5) & 1, node = j >> 6;
      int h = rt * 32 + (reg & 3) + 8 * (reg >> 2) + 4 * hl;
      float v = (a ? b1 : w2)[node * 64 + h];
      (a ? b1p : w2p)[j] = v;
    }
  }
}

// ---- kernel 2: fused MLP ---------------------------------------------------
// A = w1[node] (LDS dbuf), B = x (VGPR-resident, 64 cols/wave = xf[2][16] =
// 128 VGPRs). (256,2): 2 blocks/CU, 2 waves/SIMD. All per-node constants
// (w2/b1 permuted) live in LDS (broadcast reads) to keep peak regs < 256.

__global__ __launch_bounds__(256, 2) void fused_mlp_kernel(
    const u16* __restrict__ xpack,  // packed B-frag granules
    const u16* __restrict__ w1b,    // [256(pad)][64][256] bf16
    const float* __restrict__ b1p,  // [255][2][2][16] permuted
    const float* __restrict__ w2p,  // [255][2][2][16] permuted
    const float* __restrict__ b2,   // [255]
    float* __restrict__ no_t)       // [255][8192] node_outputs transposed
{
  __shared__ __align__(16) u16 sW[2][HID * KDIM];  // 2 x 32 KB, XOR-swizzled
  __shared__ __align__(16) float sW2[NPG * 64];    // 4 KB
  __shared__ __align__(16) float sB1[NPG * 64];    // 4 KB

  const int tid  = threadIdx.x;
  const int lane = tid & 63;
  const int wv   = tid >> 6;
  const int l31  = lane & 31;
  const int hl   = lane >> 5;
  const int nbase = blockIdx.y * NPG;
  const int ctile0 = blockIdx.x * 8 + wv * 2;  // wave's first 32-col tile

  auto stage = [&](int node, int buf) {
    const u16* base = w1b + (size_t)node * (HID * KDIM);
    char* lb = (char*)(&sW[buf][0]);
#pragma unroll
    for (int j = 0; j < 8; ++j) {
      int s = j * 256 + tid;
      int h = s >> 5;
      int kb = (s & 31) ^ (h & 31);
      gld_lds16(base + h * KDIM + kb * 8, lb + s * 16);
    }
  };

  stage(nbase, 0);
  // stage the group's permuted w2/b1 (8 KB, once)
  gld_lds16(w2p + (size_t)nbase * 64 + tid * 4, (char*)sW2 + tid * 16);
  gld_lds16(b1p + (size_t)nbase * 64 + tid * 4, (char*)sB1 + tid * 16);

  // ---- x fragments: 2 col-tiles x 16 ks, coalesced 1KB/wave loads ----
  bf16x8 xf[2][16];
#pragma unroll
  for (int ct = 0; ct < 2; ++ct) {
    const u16* src = xpack + ((size_t)(ctile0 + ct) * 16) * 512 + lane * 8;
#pragma unroll
    for (int ks = 0; ks < 16; ++ks)
      xf[ct][ks] = *(const bf16x8*)(src + ks * 512);
  }

  __syncthreads();  // drains staging vmcnt
  int buf = 0;

  for (int i = 0; i < NPG; ++i) {
    const int node = nbase + i;
    if (i + 1 < NPG) stage(node + 1, buf ^ 1);

    f32x16 acc[2][2];
#pragma unroll
    for (int rt = 0; rt < 2; ++rt)
#pragma unroll
      for (int ct = 0; ct < 2; ++ct) acc[rt][ct] = (f32x16){0};

    const char* sw = (const char*)&sW[buf][0];
#pragma unroll
    for (int ks = 0; ks < 16; ++ks) {
      int t = (ks * 2 + hl) ^ l31;
      bf16x8 a0 = *(const bf16x8*)(sw + (unsigned int)(l31 * 32 + t) * 16u);
      bf16x8 a1 = *(const bf16x8*)(sw + (unsigned int)((32 + l31) * 32 + t) * 16u);
#pragma unroll
      for (int ct = 0; ct < 2; ++ct) {
        acc[0][ct] = __builtin_amdgcn_mfma_f32_32x32x16_bf16(a0, xf[ct][ks], acc[0][ct], 0, 0, 0);
        acc[1][ct] = __builtin_amdgcn_mfma_f32_32x32x16_bf16(a1, xf[ct][ks], acc[1][ct], 0, 0, 0);
      }
    }

    // ---- epilogue: logit[b] = sum_h relu(pre+b1)*w2 ----
    // w2/b1 from LDS broadcast (uniform per half-wave) -> tiny reg footprint
    float p0 = 0.f, p1 = 0.f;
#pragma unroll
    for (int rt = 0; rt < 2; ++rt)
#pragma unroll
      for (int qd = 0; qd < 4; ++qd) {
        int o = i * 64 + hl * 32 + rt * 16 + qd * 4;
        float4 wq = *(const float4*)&sW2[o];
        float4 bq = *(const float4*)&sB1[o];
#pragma unroll
        for (int e = 0; e < 4; ++e) {
          float w = (&wq.x)[e];
          float bb = (&bq.x)[e];
          p0 += fmaxf(acc[rt][0][qd * 4 + e] + bb, 0.f) * w;
          p1 += fmaxf(acc[rt][1][qd * 4 + e] + bb, 0.f) * w;
        }
      }
    p0 += __shfl_xor(p0, 32);
    p1 += __shfl_xor(p1, 32);

    if (node < NODES) {
      float logit = (hl ? p1 : p0) + b2[node];
      float sig = 1.0f / (1.0f + expf(-logit));
      no_t[(size_t)node * BATCH + blockIdx.x * 256 + wv * 64 + lane] = sig;
    }

    __syncthreads();  // staged buf^1 drained + readers of buf done
    buf ^= 1;
  }
}

// ---- kernel 3: soft-decision-tree traversal --------------------------------

__global__ __launch_bounds__(256) void tree_kernel(
    const float* __restrict__ no_t,  // [255][8192]
    const float* __restrict__ leaf,  // [256]
    float* __restrict__ out)
{
  __shared__ float p[16][257];

  const int tid = threadIdx.x;
  const int bbase = blockIdx.x * 16;
  const int wave = tid >> 6;
  const int lane = tid & 63;

  for (int i = tid; i < NODES * 16; i += 256) {
    int n = i >> 4, r = i & 15;
    p[r][n] = no_t[(size_t)n * BATCH + bbase + r];
  }
  __syncthreads();

  float4 lw = ((const float4*)leaf)[lane];

  float* h_out  = out;
  float* pp_out = out + 8192;                            // [8192][256]
  float* no_out = out + 8192 + 8192 * 256;               // [8192][255]
  float* nr_out = out + 8192 + 8192 * 256 + 8192 * (size_t)NODES;  // [8192][255]

  for (int j = 0; j < 4; ++j) {
    const int r = wave * 4 + j;
    const int b = bbase + r;
    const float* pr = p[r];
    float* nr_b = nr_out + (size_t)b * NODES;

    float rc = 1.f;
#pragma unroll
    for (int L = 0; L < 6; ++L) {
      if (lane < (1 << L)) nr_b[(1 << L) - 1 + lane] = rc;
      float par = __shfl(rc, lane >> 1);
      float pv = pr[(1 << L) - 1 + (lane >> 1)];
      rc = par * ((lane & 1) ? pv : (1.f - pv));
    }
    nr_b[63 + lane] = rc;
    float p6 = pr[63 + lane];
    float r7a = rc * (1.f - p6), r7b = rc * p6;
    nr_b[127 + 2 * lane]     = r7a;
    nr_b[127 + 2 * lane + 1] = r7b;
    float p7a = pr[127 + 2 * lane], p7b = pr[127 + 2 * lane + 1];
    float4 pp;
    pp.x = r7a * (1.f - p7a);
    pp.y = r7a * p7a;
    pp.z = r7b * (1.f - p7b);
    pp.w = r7b * p7b;
    ((float4*)(pp_out + (size_t)b * 256))[lane] = pp;

    float* no_b = no_out + (size_t)b * NODES;
#pragma unroll
    for (int k = 0; k < 4; ++k) {
      int n = lane + 64 * k;
      if (n < NODES) no_b[n] = pr[n];
    }

    float hacc = pp.x * lw.x + pp.y * lw.y + pp.z * lw.z + pp.w * lw.w;
    hacc += __shfl_xor(hacc, 1);
    hacc += __shfl_xor(hacc, 2);
    hacc += __shfl_xor(hacc, 4);
    hacc += __shfl_xor(hacc, 8);
    hacc += __shfl_xor(hacc, 16);
    hacc += __shfl_xor(hacc, 32);
    if (lane == 0) h_out[b] = hacc;
  }
}

// ---- launcher --------------------------------------------------------------

extern "C" void kernel_launch(void* const* d_in, const int* in_sizes, int n_in,
                              void* d_out, int out_size, void* d_ws, size_t ws_size,
                              hipStream_t stream) {
  const float* x    = (const float*)d_in[0];
  const float* w1   = (const float*)d_in[1];
  const float* b1   = (const float*)d_in[2];
  const float* w2   = (const float*)d_in[3];
  const float* b2   = (const float*)d_in[4];
  const float* leaf = (const float*)d_in[5];
  float* out = (float*)d_out;

  // ws: xpack 4MB | w1b 8MB (256-node pad; node 255 poison-but-finite) |
  //     w2p 64KB | b1p 64KB | no_t 8MB
  char* ws = (char*)d_ws;
  u16*   xpack = (u16*)ws;
  u16*   w1b   = (u16*)(ws + (size_t)4194304);
  float* w2p   = (float*)(ws + (size_t)12582912);
  float* b1p   = (float*)(ws + (size_t)12648192);
  float* no_t  = (float*)(ws + (size_t)12713472);

  cvt_kernel<<<4464, 256, 0, stream>>>(x, w1, b1, w2, xpack, w1b, b1p, w2p);

  dim3 g(32, 16);  // 32 col-blocks (256 cols) x 16 node-groups = 512 blocks
  fused_mlp_kernel<<<g, 256, 0, stream>>>(xpack, w1b, b1p, w2p, b2, no_t);

  tree_kernel<<<BATCH / 16, 256, 0, stream>>>(no_t, leaf, out);
}

// Round 7
// 159.783 us; speedup vs baseline: 1.4257x; 1.0001x over previous
//
#include <hip/hip_runtime.h>
#include <cstdint>

#define BATCH   8192
#define KDIM    256
#define HID     64
#define NODES   255
#define NPG     16    // nodes per block group

typedef unsigned short u16;
typedef unsigned int u32;
typedef short bf16x8 __attribute__((ext_vector_type(8)));
typedef float f32x16 __attribute__((ext_vector_type(16)));

// ---- helpers ---------------------------------------------------------------

__device__ __forceinline__ u32 f2bf(float f) {
  u32 u = __float_as_uint(f);
  return (u + 0x7FFFu + ((u >> 16) & 1u)) >> 16;
}

__device__ __forceinline__ void gld_lds16(const void* g, void* l) {
  // async global->LDS, 16B/lane; LDS dest = wave-uniform base + lane*16
  typedef __attribute__((address_space(1))) void* gp_t;
  typedef __attribute__((address_space(3))) void* lp_t;
  gp_t gp = reinterpret_cast<gp_t>(reinterpret_cast<uintptr_t>(g));
  lp_t lp = reinterpret_cast<lp_t>(static_cast<u32>(reinterpret_cast<uintptr_t>(l)));
  __builtin_amdgcn_global_load_lds(gp, lp, 16, 0, 0);
}

// ---- kernel 1: convert + pack ----------------------------------------------
// blocks [0,256):   x -> xpack (B-fragment granule order) via LDS transpose
// blocks [256,511): w1 -> w1pk, K-MAJOR granules: granule(node,kb,h) =
//                   w1[node][h][kb*8..+8) at index node*2048 + kb*64 + h.
//                   -> fused staging is an identity copy; a-frag ds_reads are
//                   base + ks*2048 immediate offsets, conflict-free.
// blocks [511,639): w2/b1 permute into MFMA C/D register order

#define NPRM 16320     // 255*64

__global__ __launch_bounds__(256) void cvt_kernel(
    const float* __restrict__ x, const float* __restrict__ w1,
    const float* __restrict__ b1, const float* __restrict__ w2,
    u16* __restrict__ xpack, u16* __restrict__ w1pk,
    float* __restrict__ b1p, float* __restrict__ w2p) {
  const int tid = threadIdx.x;
  const int blk = blockIdx.x;

  if (blk < 256) {
    // one 32-col x tile: load 32x256 fp32 coalesced, transpose-pack via LDS
    __shared__ u16 sT[32 * 268];
    const float* xs = x + (size_t)blk * 32 * KDIM;
#pragma unroll
    for (int j = 0; j < 8; ++j) {
      int idx = j * 256 + tid;
      float4 v = ((const float4*)xs)[idx];
      int row = idx >> 6, f4 = idx & 63;
      *(u32*)&sT[row * 268 + f4 * 4]     = f2bf(v.x) | (f2bf(v.y) << 16);
      *(u32*)&sT[row * 268 + f4 * 4 + 2] = f2bf(v.z) | (f2bf(v.w) << 16);
    }
    __syncthreads();
#pragma unroll
    for (int j = 0; j < 4; ++j) {
      int d = j * 256 + tid;               // granule: ks*64 + hl*32 + l31
      int ks = d >> 6, hl = (d >> 5) & 1, l31 = d & 31;
      const u16* s8 = &sT[l31 * 268 + ks * 16 + hl * 8];
      u32 a = *(const u32*)s8, b = *(const u32*)(s8 + 2);
      u32 c = *(const u32*)(s8 + 4), e = *(const u32*)(s8 + 6);
      uint4 o = {a, b, c, e};
      ((uint4*)xpack)[(size_t)blk * 1024 + d] = o;
    }
  } else if (blk < 511) {
    // one node's w1: 64x256 fp32 -> K-major bf16 granules via LDS transpose
    __shared__ u16 sT[64 * 260];           // stride 260: aligned + 2-way banks
    const int node = blk - 256;
    const float* src = w1 + (size_t)node * (HID * KDIM);
#pragma unroll
    for (int r = 0; r < 16; ++r) {
      int idx = r * 256 + tid;
      float4 v = ((const float4*)src)[idx];
      int h = idx >> 6, f4 = idx & 63;
      uint2 o;
      o.x = f2bf(v.x) | (f2bf(v.y) << 16);
      o.y = f2bf(v.z) | (f2bf(v.w) << 16);
      *(uint2*)&sT[h * 260 + f4 * 4] = o;
    }
    __syncthreads();
    u16* dst = w1pk + (size_t)node * (HID * KDIM);
#pragma unroll
    for (int r = 0; r < 8; ++r) {
      int g = r * 256 + tid;
      int kb = g >> 6, h = g & 63;
      const u16* s8 = &sT[h * 260 + kb * 8];
      uint2 lo = *(const uint2*)s8;
      uint2 hi = *(const uint2*)(s8 + 4);
      uint4 o = {lo.x, lo.y, hi.x, hi.y};
      ((uint4*)dst)[g] = o;                // coalesced granule write
    }
  } else {
    int i2 = (blk - 511) * 256 + tid;
    if (i2 < 2 * NPRM) {
      // layout: j = node*64 + hl*32 + rt*16 + reg; value = in[node*64 + h],
      // h = rt*32 + (reg&3)+8*(reg>>2)+4*hl  (MFMA C/D row map)
      int a = i2 >= NPRM;
      int j = a ? i2 - NPRM : i2;
      int reg = j & 15, rt = (j >> 4) & 1, hl = (j >> 5) & 1, node = j >> 6;
      int h = rt * 32 + (reg & 3) + 8 * (reg >> 2) + 4 * hl;
      float v = (a ? b1 : w2)[node * 64 + h];
      (a ? b1p : w2p)[j] = v;
    }
  }
}

// ---- kernel 2: fused MLP ---------------------------------------------------
// Block = 128 batch cols x 1 node (looped x16). Wave (ch=wv>>1, rt=wv&1):
// 64 cols (ch half) x 32 hidden (rt half). xf = 128 VGPR, acc = 2 x f32x16.
// Partial logits (over 32 hidden) combined across rt-waves via LDS (parity-
// buffered, no extra barrier). w1 streamed K-major: staging = identity copy,
// a-frag reads = one base + ks*2048 immediate offsets.

__global__ void __attribute__((amdgpu_flat_work_group_size(256, 256),
                               amdgpu_waves_per_eu(2, 2)))
fused_mlp_kernel(
    const u16* __restrict__ xpack,  // packed B-frag granules
    const u16* __restrict__ w1pk,   // [256(pad)][32 kb][64 h] granules
    const float* __restrict__ b1p,  // [255][2 hl][2 rt][16] permuted
    const float* __restrict__ w2p,  // [255][2 hl][2 rt][16] permuted
    const float* __restrict__ b2,   // [255]
    float* __restrict__ no_t)       // [255][8192] node_outputs transposed
{
  __shared__ __align__(16) u16 sW[2][HID * KDIM];  // 2 x 32 KB, K-major
  __shared__ __align__(16) float sW2[NPG * 64];    // 4 KB
  __shared__ __align__(16) float sB1[NPG * 64];    // 4 KB
  __shared__ float sP[2][4][64];                   // parity x wave x col

  const int tid  = threadIdx.x;
  const int lane = tid & 63;
  const int wv   = tid >> 6;
  const int l31  = lane & 31;
  const int hl   = lane >> 5;
  const int rt   = wv & 1;
  const int ch   = wv >> 1;
  const int nbase = blockIdx.y * NPG;

  auto stage = [&](int node, int buf) {
    const u16* base = w1pk + (size_t)node * (HID * KDIM);
    char* lb = (char*)(&sW[buf][0]);
#pragma unroll
    for (int j = 0; j < 8; ++j) {
      int s = j * 256 + tid;
      gld_lds16(base + s * 8, lb + s * 16);  // identity copy, zero addr math
    }
  };

  stage(nbase, 0);
  gld_lds16(w2p + (size_t)nbase * 64 + tid * 4, (char*)sW2 + tid * 16);
  gld_lds16(b1p + (size_t)nbase * 64 + tid * 4, (char*)sB1 + tid * 16);

  // ---- x fragments: 2 col-tiles of 32 x 16 ks, coalesced ----
  const int ctile0 = blockIdx.x * 4 + ch * 2;
  bf16x8 xf[2][16];
#pragma unroll
  for (int ct = 0; ct < 2; ++ct) {
    const u16* src = xpack + ((size_t)(ctile0 + ct) * 16) * 512 + lane * 8;
#pragma unroll
    for (int ks = 0; ks < 16; ++ks)
      xf[ct][ks] = *(const bf16x8*)(src + ks * 512);
  }

  // lane's a-frag base: granule (kb = ks*2+hl, h = rt*32+l31)
  const u32 abase = (u32)(hl * 64 + rt * 32 + l31) * 16u;

  __syncthreads();  // drains staging vmcnt
  int buf = 0, par = 0;

  for (int i = 0; i < NPG; ++i) {
    const int node = nbase + i;
    if (i + 1 < NPG) stage(node + 1, buf ^ 1);

    f32x16 acc0 = (f32x16){0}, acc1 = (f32x16){0};
    const char* sw = (const char*)&sW[buf][0] + abase;
#pragma unroll
    for (int ks = 0; ks < 16; ++ks) {
      bf16x8 a = *(const bf16x8*)(sw + ks * 2048);   // immediate offsets
      acc0 = __builtin_amdgcn_mfma_f32_32x32x16_bf16(a, xf[0][ks], acc0, 0, 0, 0);
      acc1 = __builtin_amdgcn_mfma_f32_32x32x16_bf16(a, xf[1][ks], acc1, 0, 0, 0);
    }

    // ---- epilogue: partial logit over this wave's 32 hidden rows ----
    float p0 = 0.f, p1 = 0.f;
#pragma unroll
    for (int qd = 0; qd < 4; ++qd) {
      int o = i * 64 + hl * 32 + rt * 16 + qd * 4;
      float4 wq = *(const float4*)&sW2[o];
      float4 bq = *(const float4*)&sB1[o];
#pragma unroll
      for (int e = 0; e < 4; ++e) {
        float w = (&wq.x)[e];
        float bb = (&bq.x)[e];
        p0 += fmaxf(acc0[qd * 4 + e] + bb, 0.f) * w;
        p1 += fmaxf(acc1[qd * 4 + e] + bb, 0.f) * w;
      }
    }
    p0 += __shfl_xor(p0, 32);
    p1 += __shfl_xor(p1, 32);
    if (hl == 0) {
      sP[par][wv][l31]      = p0;   // col ch*64 + l31
      sP[par][wv][32 + l31] = p1;   // col ch*64 + 32 + l31
    }

    __syncthreads();  // sP visible; staged buf^1 drained; sW[buf] readers done

    if (tid < 128 && node < NODES) {
      int chh = tid >> 6, c = tid & 63;
      float logit = sP[par][chh * 2][c] + sP[par][chh * 2 + 1][c] + b2[node];
      float sig = 1.0f / (1.0f + expf(-logit));
      no_t[(size_t)node * BATCH + blockIdx.x * 128 + tid] = sig;
    }

    buf ^= 1;
    par ^= 1;  // next iter's sP writes go to the other buffer (no race)
  }
}

// ---- kernel 3: soft-decision-tree traversal --------------------------------

__global__ __launch_bounds__(256) void tree_kernel(
    const float* __restrict__ no_t,  // [255][8192]
    const float* __restrict__ leaf,  // [256]
    float* __restrict__ out)
{
  __shared__ float p[16][257];

  const int tid = threadIdx.x;
  const int bbase = blockIdx.x * 16;
  const int wave = tid >> 6;
  const int lane = tid & 63;

  for (int i = tid; i < NODES * 16; i += 256) {
    int n = i >> 4, r = i & 15;
    p[r][n] = no_t[(size_t)n * BATCH + bbase + r];
  }
  __syncthreads();

  float4 lw = ((const float4*)leaf)[lane];

  float* h_out  = out;
  float* pp_out = out + 8192;                            // [8192][256]
  float* no_out = out + 8192 + 8192 * 256;               // [8192][255]
  float* nr_out = out + 8192 + 8192 * 256 + 8192 * (size_t)NODES;  // [8192][255]

  for (int j = 0; j < 4; ++j) {
    const int r = wave * 4 + j;
    const int b = bbase + r;
    const float* pr = p[r];
    float* nr_b = nr_out + (size_t)b * NODES;

    float rc = 1.f;
#pragma unroll
    for (int L = 0; L < 6; ++L) {
      if (lane < (1 << L)) nr_b[(1 << L) - 1 + lane] = rc;
      float par = __shfl(rc, lane >> 1);
      float pv = pr[(1 << L) - 1 + (lane >> 1)];
      rc = par * ((lane & 1) ? pv : (1.f - pv));
    }
    nr_b[63 + lane] = rc;
    float p6 = pr[63 + lane];
    float r7a = rc * (1.f - p6), r7b = rc * p6;
    nr_b[127 + 2 * lane]     = r7a;
    nr_b[127 + 2 * lane + 1] = r7b;
    float p7a = pr[127 + 2 * lane], p7b = pr[127 + 2 * lane + 1];
    float4 pp;
    pp.x = r7a * (1.f - p7a);
    pp.y = r7a * p7a;
    pp.z = r7b * (1.f - p7b);
    pp.w = r7b * p7b;
    ((float4*)(pp_out + (size_t)b * 256))[lane] = pp;

    float* no_b = no_out + (size_t)b * NODES;
#pragma unroll
    for (int k = 0; k < 4; ++k) {
      int n = lane + 64 * k;
      if (n < NODES) no_b[n] = pr[n];
    }

    float hacc = pp.x * lw.x + pp.y * lw.y + pp.z * lw.z + pp.w * lw.w;
    hacc += __shfl_xor(hacc, 1);
    hacc += __shfl_xor(hacc, 2);
    hacc += __shfl_xor(hacc, 4);
    hacc += __shfl_xor(hacc, 8);
    hacc += __shfl_xor(hacc, 16);
    hacc += __shfl_xor(hacc, 32);
    if (lane == 0) h_out[b] = hacc;
  }
}

// ---- launcher --------------------------------------------------------------

extern "C" void kernel_launch(void* const* d_in, const int* in_sizes, int n_in,
                              void* d_out, int out_size, void* d_ws, size_t ws_size,
                              hipStream_t stream) {
  const float* x    = (const float*)d_in[0];
  const float* w1   = (const float*)d_in[1];
  const float* b1   = (const float*)d_in[2];
  const float* w2   = (const float*)d_in[3];
  const float* b2   = (const float*)d_in[4];
  const float* leaf = (const float*)d_in[5];
  float* out = (float*)d_out;

  // ws: xpack 4MB | w1pk 8MB (256-node pad; node 255 poison-but-finite) |
  //     w2p 64KB | b1p 64KB | no_t 8MB
  char* ws = (char*)d_ws;
  u16*   xpack = (u16*)ws;
  u16*   w1pk  = (u16*)(ws + (size_t)4194304);
  float* w2p   = (float*)(ws + (size_t)12582912);
  float* b1p   = (float*)(ws + (size_t)12648192);
  float* no_t  = (float*)(ws + (size_t)12713472);

  cvt_kernel<<<639, 256, 0, stream>>>(x, w1, b1, w2, xpack, w1pk, b1p, w2p);

  dim3 g(64, 16);  // 64 col-blocks (128 cols) x 16 node-groups = 1024 blocks
  fused_mlp_kernel<<<g, 256, 0, stream>>>(xpack, w1pk, b1p, w2p, b2, no_t);

  tree_kernel<<<BATCH / 16, 256, 0, stream>>>(no_t, leaf, out);
}